// Round 6
// baseline (114.551 us; speedup 1.0000x reference)
//
#include <hip/hip_runtime.h>

#define BB 2
#define NN 256
#define CC 256

__device__ __forceinline__ float dot4acc(float4 e, float4 w, float s) {
    s = fmaf(e.x, w.x, s); s = fmaf(e.y, w.y, s);
    s = fmaf(e.z, w.z, s); s = fmaf(e.w, w.w, s);
    return s;
}

// ---------------------------------------------------------------------------
// K1: fused q/k/v projections.  rows 0..511 = q (B*N), 512..1023 = k, 1024..1535 = v
// ---------------------------------------------------------------------------
__global__ __launch_bounds__(256) void proj_gemm(
    const float* __restrict__ q_tok, const float* __restrict__ k_tok, const float* __restrict__ v_tok,
    const float* __restrict__ Wq, const float* __restrict__ bq,
    const float* __restrict__ Wk, const float* __restrict__ bk,
    const float* __restrict__ Wv, const float* __restrict__ bv,
    float* __restrict__ out)
{
    const int row0 = blockIdx.x * 64;
    const int col0 = blockIdx.y * 64;
    const int seg  = row0 >> 9;
    const float* A    = seg == 0 ? q_tok : (seg == 1 ? k_tok : v_tok);
    const float* W    = seg == 0 ? Wq    : (seg == 1 ? Wk    : Wv);
    const float* bias = seg == 0 ? bq    : (seg == 1 ? bk    : bv);
    const int ar0 = row0 & 511;

    __shared__ float As[64][17];
    __shared__ float Bs[16][68];
    const int t  = threadIdx.x;
    const int tr = t >> 4, tc = t & 15;
    float acc[4][4] = {};

    const int sr  = t >> 2, sk4 = (t & 3) << 2;
    const int bkr = t >> 4, bj4 = (t & 15) << 2;

    for (int k0 = 0; k0 < 256; k0 += 16) {
        float4 a4 = *reinterpret_cast<const float4*>(&A[(ar0 + sr) * 256 + k0 + sk4]);
        float4 b4 = *reinterpret_cast<const float4*>(&W[(k0 + bkr) * 256 + col0 + bj4]);
        As[sr][sk4 + 0] = a4.x; As[sr][sk4 + 1] = a4.y; As[sr][sk4 + 2] = a4.z; As[sr][sk4 + 3] = a4.w;
        Bs[bkr][bj4 + 0] = b4.x; Bs[bkr][bj4 + 1] = b4.y; Bs[bkr][bj4 + 2] = b4.z; Bs[bkr][bj4 + 3] = b4.w;
        __syncthreads();
        #pragma unroll
        for (int k = 0; k < 16; ++k) {
            float a[4], bbv[4];
            #pragma unroll
            for (int i = 0; i < 4; ++i) a[i] = As[tr * 4 + i][k];
            #pragma unroll
            for (int j = 0; j < 4; ++j) bbv[j] = Bs[k][tc * 4 + j];
            #pragma unroll
            for (int i = 0; i < 4; ++i)
                #pragma unroll
                for (int j = 0; j < 4; ++j)
                    acc[i][j] = fmaf(a[i], bbv[j], acc[i][j]);
        }
        __syncthreads();
    }
    #pragma unroll
    for (int i = 0; i < 4; ++i) {
        const int r = row0 + tr * 4 + i;
        #pragma unroll
        for (int j = 0; j < 4; ++j) {
            const int cj = col0 + tc * 4 + j;
            out[r * 256 + cj] = acc[i][j] + bias[cj];
        }
    }
}

// ---------------------------------------------------------------------------
// K2: mega kernel — one block per (b,n), 512 threads (8 waves).
// Phases: 0) qrow  0b) qW = q @ Wqk^T (per-head)  1) pair scores (stream
// qk_emb 256KB)  1b/2) q.k + softmax (attn -> LDS + d_out)  3) A-accum
// (stream qv_emb 256KB)  4) hidden = attn@v + A@Wqv + bqv.
// LDS: 16KB union U + attn 4KB + pr 2KB.
// ---------------------------------------------------------------------------
__global__ __launch_bounds__(512, 4) void mega_kernel(
    const float* __restrict__ qk_emb, const float* __restrict__ qv_emb,
    const float* __restrict__ qkvp, const float* __restrict__ Wqk,
    const float* __restrict__ Wqv, const float* __restrict__ bqv,
    float* __restrict__ attn_out, float* __restrict__ hidden)
{
    const int bn = blockIdx.x;
    const int b  = bn >> 8, n = bn & 255;
    const int t  = threadIdx.x;
    const int w  = t >> 6, l = t & 63;

    __shared__ float U[4096];            // 16 KB phase-unioned
    float* qWs  = U;                     // [4][256]  (phases 0b-1)
    float* qrow = U + 1024;              // [256]     (phases 0-1b)
    float* Ssc  = U + 1280;              // [4][256]  (phases 1-2)
    float* Ap   = U;                     // [16][256] (phases 3-4, overwrites)
    __shared__ float attn_s[4][256];
    __shared__ float pr[2][256];
    __shared__ float red[16];

    // ---- phase 0: stage projected q row ----
    if (t < 256) qrow[t] = qkvp[bn * 256 + t];
    __syncthreads();

    // ---- phase 0b: qWs[h][d] = sum_c qrow[h*64+c] * Wqk[d][h*64+c] ----
    {
        const int h  = t >> 7, d0 = (t & 127) * 2;
        const float* qr = qrow + h * 64;
        const float* w0 = Wqk + (size_t)d0 * 256 + h * 64;
        const float* w1 = w0 + 256;
        float s0 = 0.f, s1 = 0.f;
        #pragma unroll
        for (int c = 0; c < 64; c += 4) {
            const float4 a  = *reinterpret_cast<const float4*>(qr + c);
            const float4 x0 = *reinterpret_cast<const float4*>(w0 + c);
            const float4 x1 = *reinterpret_cast<const float4*>(w1 + c);
            s0 = dot4acc(x0, a, s0);
            s1 = dot4acc(x1, a, s1);
        }
        qWs[h * 256 + d0]     = s0;
        qWs[h * 256 + d0 + 1] = s1;
    }
    __syncthreads();

    // ---- phase 1: pair scores.  wave w owns m in [32w, 32w+32) ----
    {
        const int lq = l & 15, lr = l >> 4;
        #pragma unroll
        for (int g = 0; g < 8; g += 2) {
            const int m0 = w * 32 + g * 4 + lr;
            const float* r0 = qk_emb + (size_t)(bn * 256 + m0) * 256 + lq * 4;
            const float* r1 = r0 + 1024;  // +4 rows
            const float4 e00 = *reinterpret_cast<const float4*>(r0);
            const float4 e01 = *reinterpret_cast<const float4*>(r0 + 64);
            const float4 e02 = *reinterpret_cast<const float4*>(r0 + 128);
            const float4 e03 = *reinterpret_cast<const float4*>(r0 + 192);
            const float4 e10 = *reinterpret_cast<const float4*>(r1);
            const float4 e11 = *reinterpret_cast<const float4*>(r1 + 64);
            const float4 e12 = *reinterpret_cast<const float4*>(r1 + 128);
            const float4 e13 = *reinterpret_cast<const float4*>(r1 + 192);
            float p0[4], p1[4];
            #pragma unroll
            for (int hh = 0; hh < 4; ++hh) {
                const float4 w0 = *reinterpret_cast<const float4*>(&qWs[hh * 256 + lq * 4]);
                const float4 w1 = *reinterpret_cast<const float4*>(&qWs[hh * 256 + 64 + lq * 4]);
                const float4 w2 = *reinterpret_cast<const float4*>(&qWs[hh * 256 + 128 + lq * 4]);
                const float4 w3 = *reinterpret_cast<const float4*>(&qWs[hh * 256 + 192 + lq * 4]);
                float s0 = 0.f, s1 = 0.f;
                s0 = dot4acc(e00, w0, s0); s0 = dot4acc(e01, w1, s0);
                s0 = dot4acc(e02, w2, s0); s0 = dot4acc(e03, w3, s0);
                s1 = dot4acc(e10, w0, s1); s1 = dot4acc(e11, w1, s1);
                s1 = dot4acc(e12, w2, s1); s1 = dot4acc(e13, w3, s1);
                p0[hh] = s0; p1[hh] = s1;
            }
            #pragma unroll
            for (int hh = 0; hh < 4; ++hh) {
                p0[hh] += __shfl_xor(p0[hh], 1); p1[hh] += __shfl_xor(p1[hh], 1);
                p0[hh] += __shfl_xor(p0[hh], 2); p1[hh] += __shfl_xor(p1[hh], 2);
                p0[hh] += __shfl_xor(p0[hh], 4); p1[hh] += __shfl_xor(p1[hh], 4);
                p0[hh] += __shfl_xor(p0[hh], 8); p1[hh] += __shfl_xor(p1[hh], 8);
            }
            if (lq == 0) {
                #pragma unroll
                for (int hh = 0; hh < 4; ++hh) {
                    Ssc[hh * 256 + m0]     = p0[hh];
                    Ssc[hh * 256 + m0 + 4] = p1[hh];
                }
            }
        }
    }
    __syncthreads();

    // ---- phase 1b + 2: q.k, softmax.  thread -> (h = t>>7, m in {j, j+128}) ----
    {
        const int h = t >> 7, j = t & 127;
        const float* k0p = qkvp + (size_t)(512 + b * 256 + j) * 256 + h * 64;
        const float* k1p = k0p + 128 * 256;
        const float* qh  = qrow + h * 64;
        float dot0 = 0.f, dot1 = 0.f;
        #pragma unroll
        for (int c = 0; c < 64; c += 4) {
            const float4 qa = *reinterpret_cast<const float4*>(qh + c);
            const float4 ka = *reinterpret_cast<const float4*>(k0p + c);
            const float4 kb = *reinterpret_cast<const float4*>(k1p + c);
            dot0 = dot4acc(ka, qa, dot0);
            dot1 = dot4acc(kb, qa, dot1);
        }
        const float sv0 = (Ssc[h * 256 + j] + dot0) * 0.125f;
        const float sv1 = (Ssc[h * 256 + j + 128] + dot1) * 0.125f;

        float mx = fmaxf(sv0, sv1);
        #pragma unroll
        for (int mask = 32; mask >= 1; mask >>= 1) mx = fmaxf(mx, __shfl_xor(mx, mask));
        if (l == 0) red[w] = mx;
        __syncthreads();
        mx = fmaxf(red[h * 2], red[h * 2 + 1]);
        const float e0 = __expf(sv0 - mx), e1 = __expf(sv1 - mx);
        float sum = e0 + e1;
        #pragma unroll
        for (int mask = 32; mask >= 1; mask >>= 1) sum += __shfl_xor(sum, mask);
        if (l == 0) red[8 + w] = sum;
        __syncthreads();
        const float inv = 1.f / (red[8 + h * 2] + red[8 + h * 2 + 1]);
        const float a0 = e0 * inv, a1 = e1 * inv;
        attn_s[h][j]       = a0;
        attn_s[h][j + 128] = a1;
        float* ao = attn_out + (size_t)((b * 4 + h) * 256 + n) * 256;
        ao[j]       = a0;
        ao[j + 128] = a1;
    }
    __syncthreads();   // Ssc/qWs/qrow dead -> U becomes Ap

    // ---- phase 3: A[h][d] accumulation.  wave w owns m in [32w,32w+32) ----
    {
        float4 acc[4];
        #pragma unroll
        for (int hh = 0; hh < 4; ++hh) acc[hh] = make_float4(0.f, 0.f, 0.f, 0.f);
        const float* rb = qv_emb + (size_t)(bn * 256 + w * 32) * 256 + l * 4;
        #pragma unroll
        for (int mm = 0; mm < 32; mm += 8) {
            float4 e[8];
            #pragma unroll
            for (int r = 0; r < 8; ++r)
                e[r] = *reinterpret_cast<const float4*>(rb + (size_t)(mm + r) * 256);
            #pragma unroll
            for (int r = 0; r < 8; ++r) {
                #pragma unroll
                for (int hh = 0; hh < 4; ++hh) {
                    const float a = attn_s[hh][w * 32 + mm + r];
                    acc[hh].x = fmaf(a, e[r].x, acc[hh].x);
                    acc[hh].y = fmaf(a, e[r].y, acc[hh].y);
                    acc[hh].z = fmaf(a, e[r].z, acc[hh].z);
                    acc[hh].w = fmaf(a, e[r].w, acc[hh].w);
                }
            }
        }
        if (w < 4) {
            #pragma unroll
            for (int hh = 0; hh < 4; ++hh)
                *reinterpret_cast<float4*>(&Ap[(w * 4 + hh) * 256 + l * 4]) = acc[hh];
        }
        __syncthreads();
        if (w >= 4) {
            #pragma unroll
            for (int hh = 0; hh < 4; ++hh) {
                float4* p = reinterpret_cast<float4*>(&Ap[((w - 4) * 4 + hh) * 256 + l * 4]);
                float4 o = *p;
                o.x += acc[hh].x; o.y += acc[hh].y; o.z += acc[hh].z; o.w += acc[hh].w;
                *p = o;
            }
        }
        __syncthreads();
        // pre-reduce 4 partials -> Afull[h][d] stored at Ap[h*256+d]
        #pragma unroll
        for (int i = 0; i < 2; ++i) {
            const int idx = t + i * 512;
            const int hh = idx >> 8, d = idx & 255;
            Ap[hh * 256 + d] = Ap[hh * 256 + d] + Ap[(4 + hh) * 256 + d]
                             + Ap[(8 + hh) * 256 + d] + Ap[(12 + hh) * 256 + d];
        }
    }
    __syncthreads();

    // ---- phase 4: hidden = attn@v + A@Wqv + bqv, split over halves ----
    {
        const int c = t & 255, half = t >> 8;
        const int hc = c >> 6;
        float hv = 0.f;
        const float* vcol = qkvp + (size_t)(1024 + b * 256 + half * 128) * 256 + c;
        #pragma unroll 8
        for (int mm = 0; mm < 128; ++mm)
            hv = fmaf(attn_s[hc][half * 128 + mm], vcol[(size_t)mm * 256], hv);
        const float* wcol = Wqv + (size_t)(half * 128) * 256 + c;
        const float* af   = Ap + hc * 256 + half * 128;
        #pragma unroll 8
        for (int dd = 0; dd < 128; ++dd)
            hv = fmaf(af[dd], wcol[(size_t)dd * 256], hv);
        pr[half][c] = hv;
    }
    __syncthreads();
    if (t < 256)
        hidden[(size_t)bn * 256 + t] = pr[0][t] + pr[1][t] + bqv[t];
}

extern "C" void kernel_launch(void* const* d_in, const int* in_sizes, int n_in,
                              void* d_out, int out_size, void* d_ws, size_t ws_size,
                              hipStream_t stream) {
    (void)in_sizes; (void)n_in; (void)out_size; (void)ws_size;
    const float* q_tok  = (const float*)d_in[0];
    const float* k_tok  = (const float*)d_in[1];
    const float* v_tok  = (const float*)d_in[2];
    const float* qk_emb = (const float*)d_in[3];
    const float* qv_emb = (const float*)d_in[4];
    const float* Wq  = (const float*)d_in[5];   const float* bq  = (const float*)d_in[6];
    const float* Wk  = (const float*)d_in[7];   const float* bk  = (const float*)d_in[8];
    const float* Wv  = (const float*)d_in[9];   const float* bv  = (const float*)d_in[10];
    const float* Wqk = (const float*)d_in[11];  /* bqk softmax-invariant */
    const float* Wqv = (const float*)d_in[13];  const float* bqv = (const float*)d_in[14];

    float* qkvp = (float*)d_ws;                 // 1536*256 floats

    float* hidden = (float*)d_out;
    float* attn   = (float*)d_out + BB * NN * CC;

    proj_gemm  <<<dim3(24, 4), 256, 0, stream>>>(q_tok, k_tok, v_tok, Wq, bq, Wk, bk, Wv, bv, qkvp);
    mega_kernel<<<512,         512, 0, stream>>>(qk_emb, qv_emb, qkvp, Wqk, Wqv, bqv, attn, hidden);
}

// Round 7
// 93.622 us; speedup vs baseline: 1.2235x; 1.2235x over previous
//
#include <hip/hip_runtime.h>

#define BB 2
#define NN 256
#define CC 256

__device__ __forceinline__ float dot4acc(float4 e, float4 w, float s) {
    s = fmaf(e.x, w.x, s); s = fmaf(e.y, w.y, s);
    s = fmaf(e.z, w.z, s); s = fmaf(e.w, w.w, s);
    return s;
}

// ---------------------------------------------------------------------------
// K1: fused q/k/v projections.  rows 0..511 = q (B*N), 512..1023 = k, 1024..1535 = v
// ---------------------------------------------------------------------------
__global__ __launch_bounds__(256) void proj_gemm(
    const float* __restrict__ q_tok, const float* __restrict__ k_tok, const float* __restrict__ v_tok,
    const float* __restrict__ Wq, const float* __restrict__ bq,
    const float* __restrict__ Wk, const float* __restrict__ bk,
    const float* __restrict__ Wv, const float* __restrict__ bv,
    float* __restrict__ out)
{
    const int row0 = blockIdx.x * 64;
    const int col0 = blockIdx.y * 64;
    const int seg  = row0 >> 9;
    const float* A    = seg == 0 ? q_tok : (seg == 1 ? k_tok : v_tok);
    const float* W    = seg == 0 ? Wq    : (seg == 1 ? Wk    : Wv);
    const float* bias = seg == 0 ? bq    : (seg == 1 ? bk    : bv);
    const int ar0 = row0 & 511;

    __shared__ float As[64][17];
    __shared__ float Bs[16][68];
    const int t  = threadIdx.x;
    const int tr = t >> 4, tc = t & 15;
    float acc[4][4] = {};

    const int sr  = t >> 2, sk4 = (t & 3) << 2;
    const int bkr = t >> 4, bj4 = (t & 15) << 2;

    for (int k0 = 0; k0 < 256; k0 += 16) {
        float4 a4 = *reinterpret_cast<const float4*>(&A[(ar0 + sr) * 256 + k0 + sk4]);
        float4 b4 = *reinterpret_cast<const float4*>(&W[(k0 + bkr) * 256 + col0 + bj4]);
        As[sr][sk4 + 0] = a4.x; As[sr][sk4 + 1] = a4.y; As[sr][sk4 + 2] = a4.z; As[sr][sk4 + 3] = a4.w;
        Bs[bkr][bj4 + 0] = b4.x; Bs[bkr][bj4 + 1] = b4.y; Bs[bkr][bj4 + 2] = b4.z; Bs[bkr][bj4 + 3] = b4.w;
        __syncthreads();
        #pragma unroll
        for (int k = 0; k < 16; ++k) {
            float a[4], bbv[4];
            #pragma unroll
            for (int i = 0; i < 4; ++i) a[i] = As[tr * 4 + i][k];
            #pragma unroll
            for (int j = 0; j < 4; ++j) bbv[j] = Bs[k][tc * 4 + j];
            #pragma unroll
            for (int i = 0; i < 4; ++i)
                #pragma unroll
                for (int j = 0; j < 4; ++j)
                    acc[i][j] = fmaf(a[i], bbv[j], acc[i][j]);
        }
        __syncthreads();
    }
    #pragma unroll
    for (int i = 0; i < 4; ++i) {
        const int r = row0 + tr * 4 + i;
        #pragma unroll
        for (int j = 0; j < 4; ++j) {
            const int cj = col0 + tc * 4 + j;
            out[r * 256 + cj] = acc[i][j] + bias[cj];
        }
    }
}

// ---------------------------------------------------------------------------
// K2: qW[bn][h][d] = sum_c qp[bn][h*64+c] * Wqk[d][h*64+c]   (coalesced tiled)
// ---------------------------------------------------------------------------
__global__ __launch_bounds__(256) void qw_gemm(
    const float* __restrict__ qp, const float* __restrict__ Wqk, float* __restrict__ qW)
{
    const int h    = blockIdx.z;
    const int row0 = blockIdx.x * 64;
    const int d0   = blockIdx.y * 64;
    __shared__ float As[64][17];
    __shared__ float Bs[16][68];
    const int t  = threadIdx.x;
    const int tr = t >> 4, tc = t & 15;
    float acc[4][4] = {};
    const int sr = t >> 2, sc4 = (t & 3) << 2;

    for (int k0 = 0; k0 < 64; k0 += 16) {
        float4 a4 = *reinterpret_cast<const float4*>(&qp[(row0 + sr) * 256 + h * 64 + k0 + sc4]);
        float4 b4 = *reinterpret_cast<const float4*>(&Wqk[(d0 + sr) * 256 + h * 64 + k0 + sc4]);
        As[sr][sc4 + 0] = a4.x; As[sr][sc4 + 1] = a4.y; As[sr][sc4 + 2] = a4.z; As[sr][sc4 + 3] = a4.w;
        Bs[sc4 + 0][sr] = b4.x; Bs[sc4 + 1][sr] = b4.y; Bs[sc4 + 2][sr] = b4.z; Bs[sc4 + 3][sr] = b4.w;
        __syncthreads();
        #pragma unroll
        for (int k = 0; k < 16; ++k) {
            float a[4], bbv[4];
            #pragma unroll
            for (int i = 0; i < 4; ++i) a[i] = As[tr * 4 + i][k];
            #pragma unroll
            for (int j = 0; j < 4; ++j) bbv[j] = Bs[k][tc * 4 + j];
            #pragma unroll
            for (int i = 0; i < 4; ++i)
                #pragma unroll
                for (int j = 0; j < 4; ++j)
                    acc[i][j] = fmaf(a[i], bbv[j], acc[i][j]);
        }
        __syncthreads();
    }
    #pragma unroll
    for (int i = 0; i < 4; ++i)
        #pragma unroll
        for (int j = 0; j < 4; ++j)
            qW[((row0 + tr * 4 + i) * 4 + h) * 256 + d0 + tc * 4 + j] = acc[i][j];
}

// ---------------------------------------------------------------------------
// K3: Sqk[((b*4+h)*256+n)*256+m] = sum_c q[b,n,h*64+c] * k[b,m,h*64+c]  (raw)
// ---------------------------------------------------------------------------
__global__ __launch_bounds__(256) void qk_gemm(
    const float* __restrict__ qkvp, float* __restrict__ Sqk)
{
    const int bh = blockIdx.z;
    const int b  = bh >> 2, h = bh & 3;
    const int n0 = blockIdx.x * 64;
    const int m0 = blockIdx.y * 64;
    __shared__ float As[64][17];
    __shared__ float Bs[16][68];
    const int t  = threadIdx.x;
    const int tr = t >> 4, tc = t & 15;
    float acc[4][4] = {};
    const int sr = t >> 2, sc4 = (t & 3) << 2;

    for (int k0 = 0; k0 < 64; k0 += 16) {
        float4 a4 = *reinterpret_cast<const float4*>(&qkvp[(size_t)(b * 256 + n0 + sr) * 256 + h * 64 + k0 + sc4]);
        float4 b4 = *reinterpret_cast<const float4*>(&qkvp[(size_t)(512 + b * 256 + m0 + sr) * 256 + h * 64 + k0 + sc4]);
        As[sr][sc4 + 0] = a4.x; As[sr][sc4 + 1] = a4.y; As[sr][sc4 + 2] = a4.z; As[sr][sc4 + 3] = a4.w;
        Bs[sc4 + 0][sr] = b4.x; Bs[sc4 + 1][sr] = b4.y; Bs[sc4 + 2][sr] = b4.z; Bs[sc4 + 3][sr] = b4.w;
        __syncthreads();
        #pragma unroll
        for (int k = 0; k < 16; ++k) {
            float a[4], bbv[4];
            #pragma unroll
            for (int i = 0; i < 4; ++i) a[i] = As[tr * 4 + i][k];
            #pragma unroll
            for (int j = 0; j < 4; ++j) bbv[j] = Bs[k][tc * 4 + j];
            #pragma unroll
            for (int i = 0; i < 4; ++i)
                #pragma unroll
                for (int j = 0; j < 4; ++j)
                    acc[i][j] = fmaf(a[i], bbv[j], acc[i][j]);
        }
        __syncthreads();
    }
    #pragma unroll
    for (int i = 0; i < 4; ++i)
        #pragma unroll
        for (int j = 0; j < 4; ++j)
            Sqk[(size_t)((b * 4 + h) * 256 + n0 + tr * 4 + i) * 256 + m0 + tc * 4 + j] = acc[i][j];
}

// ---------------------------------------------------------------------------
// K4: mega2 — one block per (b,n), 512 threads (8 waves).  NO address-
// divergent VMEM: every global load is row-contiguous per wave.
// Phases: A) qWs stage  1) pair scores (stream qk_emb)  2) softmax (Sqk rows)
// 3) A-accum (stream qv_emb)  4) attn@v + A@Wqv via LDS-staged 16-row tiles.
// ---------------------------------------------------------------------------
__global__ __launch_bounds__(512, 4) void mega2(
    const float* __restrict__ qk_emb, const float* __restrict__ qv_emb,
    const float* __restrict__ qkvp, const float* __restrict__ qW,
    const float* __restrict__ Sqk, const float* __restrict__ Wqv,
    const float* __restrict__ bqv,
    float* __restrict__ attn_out, float* __restrict__ hidden)
{
    const int bn = blockIdx.x;
    const int b  = bn >> 8, n = bn & 255;
    const int t  = threadIdx.x;
    const int w  = t >> 6, l = t & 63;

    __shared__ float U[4096];            // 16 KB phase-unioned
    float* qWs = U;                      // [4][256]  (phases A-1)
    float* Ssc = U + 1024;               // [4][256]  (phases 1-2)
    float* Ap  = U;                      // [16][256] (phase 3); [4][256] after reduce
    __shared__ float attn_s[4][256];
    __shared__ float stage[16][256];     // 16 KB tile staging (phase 4)
    __shared__ float pr[2][256];
    __shared__ float red[16];

    // ---- phase A: stage qW row (contiguous 4 KB) ----
    if (t < 256)
        *reinterpret_cast<float4*>(&U[t * 4]) =
            *reinterpret_cast<const float4*>(&qW[(size_t)bn * 1024 + t * 4]);
    __syncthreads();

    // ---- phase 1: pair scores.  wave w owns m in [32w, 32w+32) ----
    {
        const int lq = l & 15, lr = l >> 4;
        #pragma unroll
        for (int g = 0; g < 8; g += 2) {
            const int m0 = w * 32 + g * 4 + lr;
            const float* r0 = qk_emb + (size_t)(bn * 256 + m0) * 256 + lq * 4;
            const float* r1 = r0 + 1024;  // +4 rows
            const float4 e00 = *reinterpret_cast<const float4*>(r0);
            const float4 e01 = *reinterpret_cast<const float4*>(r0 + 64);
            const float4 e02 = *reinterpret_cast<const float4*>(r0 + 128);
            const float4 e03 = *reinterpret_cast<const float4*>(r0 + 192);
            const float4 e10 = *reinterpret_cast<const float4*>(r1);
            const float4 e11 = *reinterpret_cast<const float4*>(r1 + 64);
            const float4 e12 = *reinterpret_cast<const float4*>(r1 + 128);
            const float4 e13 = *reinterpret_cast<const float4*>(r1 + 192);
            float p0[4], p1[4];
            #pragma unroll
            for (int hh = 0; hh < 4; ++hh) {
                const float4 w0 = *reinterpret_cast<const float4*>(&qWs[hh * 256 + lq * 4]);
                const float4 w1 = *reinterpret_cast<const float4*>(&qWs[hh * 256 + 64 + lq * 4]);
                const float4 w2 = *reinterpret_cast<const float4*>(&qWs[hh * 256 + 128 + lq * 4]);
                const float4 w3 = *reinterpret_cast<const float4*>(&qWs[hh * 256 + 192 + lq * 4]);
                float s0 = 0.f, s1 = 0.f;
                s0 = dot4acc(e00, w0, s0); s0 = dot4acc(e01, w1, s0);
                s0 = dot4acc(e02, w2, s0); s0 = dot4acc(e03, w3, s0);
                s1 = dot4acc(e10, w0, s1); s1 = dot4acc(e11, w1, s1);
                s1 = dot4acc(e12, w2, s1); s1 = dot4acc(e13, w3, s1);
                p0[hh] = s0; p1[hh] = s1;
            }
            #pragma unroll
            for (int hh = 0; hh < 4; ++hh) {
                p0[hh] += __shfl_xor(p0[hh], 1); p1[hh] += __shfl_xor(p1[hh], 1);
                p0[hh] += __shfl_xor(p0[hh], 2); p1[hh] += __shfl_xor(p1[hh], 2);
                p0[hh] += __shfl_xor(p0[hh], 4); p1[hh] += __shfl_xor(p1[hh], 4);
                p0[hh] += __shfl_xor(p0[hh], 8); p1[hh] += __shfl_xor(p1[hh], 8);
            }
            if (lq == 0) {
                #pragma unroll
                for (int hh = 0; hh < 4; ++hh) {
                    Ssc[hh * 256 + m0]     = p0[hh];
                    Ssc[hh * 256 + m0 + 4] = p1[hh];
                }
            }
        }
    }
    __syncthreads();

    // ---- phase 2: softmax.  thread -> (h = t>>7, m in {j, j+128}); Sqk rows coalesced ----
    {
        const int h = t >> 7, j = t & 127;
        const size_t srow = (size_t)((b * 4 + h) * 256 + n) * 256;
        const float sv0 = (Ssc[h * 256 + j]       + Sqk[srow + j])       * 0.125f;
        const float sv1 = (Ssc[h * 256 + j + 128] + Sqk[srow + j + 128]) * 0.125f;

        float mx = fmaxf(sv0, sv1);
        #pragma unroll
        for (int mask = 32; mask >= 1; mask >>= 1) mx = fmaxf(mx, __shfl_xor(mx, mask));
        if (l == 0) red[w] = mx;
        __syncthreads();
        mx = fmaxf(red[h * 2], red[h * 2 + 1]);
        const float e0 = __expf(sv0 - mx), e1 = __expf(sv1 - mx);
        float sum = e0 + e1;
        #pragma unroll
        for (int mask = 32; mask >= 1; mask >>= 1) sum += __shfl_xor(sum, mask);
        if (l == 0) red[8 + w] = sum;
        __syncthreads();
        const float inv = 1.f / (red[8 + h * 2] + red[8 + h * 2 + 1]);
        const float a0 = e0 * inv, a1 = e1 * inv;
        attn_s[h][j]       = a0;
        attn_s[h][j + 128] = a1;
        float* ao = attn_out + (size_t)((b * 4 + h) * 256 + n) * 256;
        ao[j]       = a0;
        ao[j + 128] = a1;
    }
    __syncthreads();   // Ssc/qWs dead -> U becomes Ap

    // ---- phase 3: A[h][d] accumulation.  wave w owns m in [32w,32w+32) ----
    {
        float4 acc[4];
        #pragma unroll
        for (int hh = 0; hh < 4; ++hh) acc[hh] = make_float4(0.f, 0.f, 0.f, 0.f);
        const float* rb = qv_emb + (size_t)(bn * 256 + w * 32) * 256 + l * 4;
        #pragma unroll
        for (int mm = 0; mm < 32; mm += 8) {
            float4 e[8];
            #pragma unroll
            for (int r = 0; r < 8; ++r)
                e[r] = *reinterpret_cast<const float4*>(rb + (size_t)(mm + r) * 256);
            #pragma unroll
            for (int r = 0; r < 8; ++r) {
                #pragma unroll
                for (int hh = 0; hh < 4; ++hh) {
                    const float a = attn_s[hh][w * 32 + mm + r];
                    acc[hh].x = fmaf(a, e[r].x, acc[hh].x);
                    acc[hh].y = fmaf(a, e[r].y, acc[hh].y);
                    acc[hh].z = fmaf(a, e[r].z, acc[hh].z);
                    acc[hh].w = fmaf(a, e[r].w, acc[hh].w);
                }
            }
        }
        if (w < 4) {
            #pragma unroll
            for (int hh = 0; hh < 4; ++hh)
                *reinterpret_cast<float4*>(&Ap[(w * 4 + hh) * 256 + l * 4]) = acc[hh];
        }
        __syncthreads();
        if (w >= 4) {
            #pragma unroll
            for (int hh = 0; hh < 4; ++hh) {
                float4* p = reinterpret_cast<float4*>(&Ap[((w - 4) * 4 + hh) * 256 + l * 4]);
                float4 o = *p;
                o.x += acc[hh].x; o.y += acc[hh].y; o.z += acc[hh].z; o.w += acc[hh].w;
                *p = o;
            }
        }
        __syncthreads();
        // pre-reduce 4 partials -> Afull[h][d] at U[h*256+d]
        #pragma unroll
        for (int i = 0; i < 2; ++i) {
            const int idx = t + i * 512;
            const int hh = idx >> 8, d = idx & 255;
            Ap[hh * 256 + d] = Ap[hh * 256 + d] + Ap[(4 + hh) * 256 + d]
                             + Ap[(8 + hh) * 256 + d] + Ap[(12 + hh) * 256 + d];
        }
    }
    __syncthreads();

    // ---- phase 4: hidden = attn@v + A@Wqv + bqv via LDS-staged 16-row tiles ----
    {
        const int c = t & 255, half = t >> 8, hc = c >> 6;
        float hv = 0.f;
        // 4a: attn @ v   (v rows of qkvp, coalesced 1 KB per wave-inst)
        for (int mt = 0; mt < 16; ++mt) {
            #pragma unroll
            for (int i = 0; i < 2; ++i) {
                const int fidx = t + i * 512;          // float4 index in 16x256 tile
                const int row = fidx >> 6, col4 = (fidx & 63) * 4;
                *reinterpret_cast<float4*>(&stage[row][col4]) =
                    *reinterpret_cast<const float4*>(
                        &qkvp[(size_t)(1024 + b * 256 + mt * 16 + row) * 256 + col4]);
            }
            __syncthreads();
            #pragma unroll
            for (int r = 0; r < 8; ++r)
                hv = fmaf(attn_s[hc][mt * 16 + half * 8 + r], stage[half * 8 + r][c], hv);
            __syncthreads();
        }
        // 4b: A @ Wqv    (Wqv rows, coalesced)
        for (int dt = 0; dt < 16; ++dt) {
            #pragma unroll
            for (int i = 0; i < 2; ++i) {
                const int fidx = t + i * 512;
                const int row = fidx >> 6, col4 = (fidx & 63) * 4;
                *reinterpret_cast<float4*>(&stage[row][col4]) =
                    *reinterpret_cast<const float4*>(&Wqv[(size_t)(dt * 16 + row) * 256 + col4]);
            }
            __syncthreads();
            #pragma unroll
            for (int r = 0; r < 8; ++r)
                hv = fmaf(U[hc * 256 + dt * 16 + half * 8 + r], stage[half * 8 + r][c], hv);
            __syncthreads();
        }
        pr[half][c] = hv;
    }
    __syncthreads();
    if (t < 256)
        hidden[(size_t)bn * 256 + t] = pr[0][t] + pr[1][t] + bqv[t];
}

extern "C" void kernel_launch(void* const* d_in, const int* in_sizes, int n_in,
                              void* d_out, int out_size, void* d_ws, size_t ws_size,
                              hipStream_t stream) {
    (void)in_sizes; (void)n_in; (void)out_size; (void)ws_size;
    const float* q_tok  = (const float*)d_in[0];
    const float* k_tok  = (const float*)d_in[1];
    const float* v_tok  = (const float*)d_in[2];
    const float* qk_emb = (const float*)d_in[3];
    const float* qv_emb = (const float*)d_in[4];
    const float* Wq  = (const float*)d_in[5];   const float* bq  = (const float*)d_in[6];
    const float* Wk  = (const float*)d_in[7];   const float* bk  = (const float*)d_in[8];
    const float* Wv  = (const float*)d_in[9];   const float* bv  = (const float*)d_in[10];
    const float* Wqk = (const float*)d_in[11];  /* bqk softmax-invariant */
    const float* Wqv = (const float*)d_in[13];  const float* bqv = (const float*)d_in[14];

    float* ws   = (float*)d_ws;
    float* qkvp = ws;                      // 1536*256 = 393216
    float* qW   = ws + 393216;             // 512*1024 = 524288
    float* Sqk  = ws + 917504;             // 2048*256 = 524288

    float* hidden = (float*)d_out;
    float* attn   = (float*)d_out + BB * NN * CC;

    proj_gemm<<<dim3(24, 4),   256, 0, stream>>>(q_tok, k_tok, v_tok, Wq, bq, Wk, bk, Wv, bv, qkvp);
    qw_gemm  <<<dim3(8, 4, 4), 256, 0, stream>>>(qkvp, Wqk, qW);
    qk_gemm  <<<dim3(4, 4, 8), 256, 0, stream>>>(qkvp, Sqk);
    mega2    <<<512,           512, 0, stream>>>(qk_emb, qv_emb, qkvp, qW, Sqk, Wqv, bqv, attn, hidden);
}

// Round 8
// 92.134 us; speedup vs baseline: 1.2433x; 1.0161x over previous
//
#include <hip/hip_runtime.h>

#define BB 2
#define NN 256
#define CC 256

__device__ __forceinline__ float dot4acc(float4 e, float4 w, float s) {
    s = fmaf(e.x, w.x, s); s = fmaf(e.y, w.y, s);
    s = fmaf(e.z, w.z, s); s = fmaf(e.w, w.w, s);
    return s;
}

// ---------------------------------------------------------------------------
// K1: fused q/k/v projections.  rows 0..511 = q (B*N), 512..1023 = k, 1024..1535 = v
// ---------------------------------------------------------------------------
__global__ __launch_bounds__(256) void proj_gemm(
    const float* __restrict__ q_tok, const float* __restrict__ k_tok, const float* __restrict__ v_tok,
    const float* __restrict__ Wq, const float* __restrict__ bq,
    const float* __restrict__ Wk, const float* __restrict__ bk,
    const float* __restrict__ Wv, const float* __restrict__ bv,
    float* __restrict__ out)
{
    const int row0 = blockIdx.x * 64;
    const int col0 = blockIdx.y * 64;
    const int seg  = row0 >> 9;
    const float* A    = seg == 0 ? q_tok : (seg == 1 ? k_tok : v_tok);
    const float* W    = seg == 0 ? Wq    : (seg == 1 ? Wk    : Wv);
    const float* bias = seg == 0 ? bq    : (seg == 1 ? bk    : bv);
    const int ar0 = row0 & 511;

    __shared__ float As[64][17];
    __shared__ float Bs[16][68];
    const int t  = threadIdx.x;
    const int tr = t >> 4, tc = t & 15;
    float acc[4][4] = {};

    const int sr  = t >> 2, sk4 = (t & 3) << 2;
    const int bkr = t >> 4, bj4 = (t & 15) << 2;

    for (int k0 = 0; k0 < 256; k0 += 16) {
        float4 a4 = *reinterpret_cast<const float4*>(&A[(ar0 + sr) * 256 + k0 + sk4]);
        float4 b4 = *reinterpret_cast<const float4*>(&W[(k0 + bkr) * 256 + col0 + bj4]);
        As[sr][sk4 + 0] = a4.x; As[sr][sk4 + 1] = a4.y; As[sr][sk4 + 2] = a4.z; As[sr][sk4 + 3] = a4.w;
        Bs[bkr][bj4 + 0] = b4.x; Bs[bkr][bj4 + 1] = b4.y; Bs[bkr][bj4 + 2] = b4.z; Bs[bkr][bj4 + 3] = b4.w;
        __syncthreads();
        #pragma unroll
        for (int k = 0; k < 16; ++k) {
            float a[4], bbv[4];
            #pragma unroll
            for (int i = 0; i < 4; ++i) a[i] = As[tr * 4 + i][k];
            #pragma unroll
            for (int j = 0; j < 4; ++j) bbv[j] = Bs[k][tc * 4 + j];
            #pragma unroll
            for (int i = 0; i < 4; ++i)
                #pragma unroll
                for (int j = 0; j < 4; ++j)
                    acc[i][j] = fmaf(a[i], bbv[j], acc[i][j]);
        }
        __syncthreads();
    }
    #pragma unroll
    for (int i = 0; i < 4; ++i) {
        const int r = row0 + tr * 4 + i;
        #pragma unroll
        for (int j = 0; j < 4; ++j) {
            const int cj = col0 + tc * 4 + j;
            out[r * 256 + cj] = acc[i][j] + bias[cj];
        }
    }
}

// ---------------------------------------------------------------------------
// K2: qW[bn][h][d] = sum_c qp[bn][h*64+c] * Wqk[d][h*64+c]   (coalesced tiled)
// ---------------------------------------------------------------------------
__global__ __launch_bounds__(256) void qw_gemm(
    const float* __restrict__ qp, const float* __restrict__ Wqk, float* __restrict__ qW)
{
    const int h    = blockIdx.z;
    const int row0 = blockIdx.x * 64;
    const int d0   = blockIdx.y * 64;
    __shared__ float As[64][17];
    __shared__ float Bs[16][68];
    const int t  = threadIdx.x;
    const int tr = t >> 4, tc = t & 15;
    float acc[4][4] = {};
    const int sr = t >> 2, sc4 = (t & 3) << 2;

    for (int k0 = 0; k0 < 64; k0 += 16) {
        float4 a4 = *reinterpret_cast<const float4*>(&qp[(row0 + sr) * 256 + h * 64 + k0 + sc4]);
        float4 b4 = *reinterpret_cast<const float4*>(&Wqk[(d0 + sr) * 256 + h * 64 + k0 + sc4]);
        As[sr][sc4 + 0] = a4.x; As[sr][sc4 + 1] = a4.y; As[sr][sc4 + 2] = a4.z; As[sr][sc4 + 3] = a4.w;
        Bs[sc4 + 0][sr] = b4.x; Bs[sc4 + 1][sr] = b4.y; Bs[sc4 + 2][sr] = b4.z; Bs[sc4 + 3][sr] = b4.w;
        __syncthreads();
        #pragma unroll
        for (int k = 0; k < 16; ++k) {
            float a[4], bbv[4];
            #pragma unroll
            for (int i = 0; i < 4; ++i) a[i] = As[tr * 4 + i][k];
            #pragma unroll
            for (int j = 0; j < 4; ++j) bbv[j] = Bs[k][tc * 4 + j];
            #pragma unroll
            for (int i = 0; i < 4; ++i)
                #pragma unroll
                for (int j = 0; j < 4; ++j)
                    acc[i][j] = fmaf(a[i], bbv[j], acc[i][j]);
        }
        __syncthreads();
    }
    #pragma unroll
    for (int i = 0; i < 4; ++i)
        #pragma unroll
        for (int j = 0; j < 4; ++j)
            qW[((row0 + tr * 4 + i) * 4 + h) * 256 + d0 + tc * 4 + j] = acc[i][j];
}

// ---------------------------------------------------------------------------
// K3: Sqk[((b*4+h)*256+n)*256+m] = sum_c q[b,n,h*64+c] * k[b,m,h*64+c]  (raw)
// ---------------------------------------------------------------------------
__global__ __launch_bounds__(256) void qk_gemm(
    const float* __restrict__ qkvp, float* __restrict__ Sqk)
{
    const int bh = blockIdx.z;
    const int b  = bh >> 2, h = bh & 3;
    const int n0 = blockIdx.x * 64;
    const int m0 = blockIdx.y * 64;
    __shared__ float As[64][17];
    __shared__ float Bs[16][68];
    const int t  = threadIdx.x;
    const int tr = t >> 4, tc = t & 15;
    float acc[4][4] = {};
    const int sr = t >> 2, sc4 = (t & 3) << 2;

    for (int k0 = 0; k0 < 64; k0 += 16) {
        float4 a4 = *reinterpret_cast<const float4*>(&qkvp[(size_t)(b * 256 + n0 + sr) * 256 + h * 64 + k0 + sc4]);
        float4 b4 = *reinterpret_cast<const float4*>(&qkvp[(size_t)(512 + b * 256 + m0 + sr) * 256 + h * 64 + k0 + sc4]);
        As[sr][sc4 + 0] = a4.x; As[sr][sc4 + 1] = a4.y; As[sr][sc4 + 2] = a4.z; As[sr][sc4 + 3] = a4.w;
        Bs[sc4 + 0][sr] = b4.x; Bs[sc4 + 1][sr] = b4.y; Bs[sc4 + 2][sr] = b4.z; Bs[sc4 + 3][sr] = b4.w;
        __syncthreads();
        #pragma unroll
        for (int k = 0; k < 16; ++k) {
            float a[4], bbv[4];
            #pragma unroll
            for (int i = 0; i < 4; ++i) a[i] = As[tr * 4 + i][k];
            #pragma unroll
            for (int j = 0; j < 4; ++j) bbv[j] = Bs[k][tc * 4 + j];
            #pragma unroll
            for (int i = 0; i < 4; ++i)
                #pragma unroll
                for (int j = 0; j < 4; ++j)
                    acc[i][j] = fmaf(a[i], bbv[j], acc[i][j]);
        }
        __syncthreads();
    }
    #pragma unroll
    for (int i = 0; i < 4; ++i)
        #pragma unroll
        for (int j = 0; j < 4; ++j)
            Sqk[(size_t)((b * 4 + h) * 256 + n0 + tr * 4 + i) * 256 + m0 + tc * 4 + j] = acc[i][j];
}

// ---------------------------------------------------------------------------
// K4: mega3 — one block per (b,n), 512 threads (8 waves).
// ONLINE-SOFTMAX: each wave owns 32 m-rows and runs the ENTIRE streaming
// section (Sqk seg + qk_emb pair scores + wave-local max/exp/sum + qv_emb
// A-accumulation) with ZERO cross-wave barriers.  One barrier merges the
// per-wave stats exactly; phase 4 uses register-double-buffered tiles.
// ---------------------------------------------------------------------------
__global__ __launch_bounds__(512, 4) void mega3(
    const float* __restrict__ qk_emb, const float* __restrict__ qv_emb,
    const float* __restrict__ qkvp, const float* __restrict__ qW,
    const float* __restrict__ Sqk, const float* __restrict__ Wqv,
    const float* __restrict__ bqv,
    float* __restrict__ attn_out, float* __restrict__ hidden)
{
    const int bn = blockIdx.x;
    const int b  = bn >> 8, n = bn & 255;
    const int t  = threadIdx.x;
    const int w  = t >> 6, l = t & 63;

    __shared__ float qWs[1024];          // [h][d]
    __shared__ float SqkL[1024];         // [h][m]  raw q.k
    __shared__ float Ssc[1024];          // [h][m]  raw pair scores
    __shared__ float attn_s[1024];       // [h][m]  e -> later normalized attn
    __shared__ float Ap[4096];           // [16][256] A partials; [4][256] after reduce
    __shared__ float stage[16][256];
    __shared__ float pr[2][256];
    __shared__ float mxs[8][4], sums[8][4], scl[8][4];

    // ---- stage qW (contiguous 4 KB) ----
    if (t < 256)
        *reinterpret_cast<float4*>(&qWs[t * 4]) =
            *reinterpret_cast<const float4*>(&qW[(size_t)bn * 1024 + t * 4]);
    __syncthreads();

    const int lq = l & 15, lr = l >> 4, li = l & 31;

    // ================= wave-independent streaming (no barriers) =============
    // sub-pass 0: this wave's Sqk segment (coalesced 128B loads)
    if (l < 32) {
        #pragma unroll
        for (int h = 0; h < 4; ++h)
            SqkL[h * 256 + w * 32 + li] =
                Sqk[(size_t)((b * 4 + h) * 256 + n) * 256 + w * 32 + li];
    }

    // sub-pass 1: pair scores for rows [32w, 32w+32)
    #pragma unroll
    for (int g = 0; g < 8; g += 2) {
        const int m0 = w * 32 + g * 4 + lr;
        const float* r0 = qk_emb + (size_t)(bn * 256 + m0) * 256 + lq * 4;
        const float* r1 = r0 + 1024;  // +4 rows
        const float4 e00 = *reinterpret_cast<const float4*>(r0);
        const float4 e01 = *reinterpret_cast<const float4*>(r0 + 64);
        const float4 e02 = *reinterpret_cast<const float4*>(r0 + 128);
        const float4 e03 = *reinterpret_cast<const float4*>(r0 + 192);
        const float4 e10 = *reinterpret_cast<const float4*>(r1);
        const float4 e11 = *reinterpret_cast<const float4*>(r1 + 64);
        const float4 e12 = *reinterpret_cast<const float4*>(r1 + 128);
        const float4 e13 = *reinterpret_cast<const float4*>(r1 + 192);
        float p0[4], p1[4];
        #pragma unroll
        for (int hh = 0; hh < 4; ++hh) {
            const float4 w0 = *reinterpret_cast<const float4*>(&qWs[hh * 256 + lq * 4]);
            const float4 w1 = *reinterpret_cast<const float4*>(&qWs[hh * 256 + 64 + lq * 4]);
            const float4 w2 = *reinterpret_cast<const float4*>(&qWs[hh * 256 + 128 + lq * 4]);
            const float4 w3 = *reinterpret_cast<const float4*>(&qWs[hh * 256 + 192 + lq * 4]);
            float s0 = 0.f, s1 = 0.f;
            s0 = dot4acc(e00, w0, s0); s0 = dot4acc(e01, w1, s0);
            s0 = dot4acc(e02, w2, s0); s0 = dot4acc(e03, w3, s0);
            s1 = dot4acc(e10, w0, s1); s1 = dot4acc(e11, w1, s1);
            s1 = dot4acc(e12, w2, s1); s1 = dot4acc(e13, w3, s1);
            p0[hh] = s0; p1[hh] = s1;
        }
        #pragma unroll
        for (int hh = 0; hh < 4; ++hh) {
            p0[hh] += __shfl_xor(p0[hh], 1); p1[hh] += __shfl_xor(p1[hh], 1);
            p0[hh] += __shfl_xor(p0[hh], 2); p1[hh] += __shfl_xor(p1[hh], 2);
            p0[hh] += __shfl_xor(p0[hh], 4); p1[hh] += __shfl_xor(p1[hh], 4);
            p0[hh] += __shfl_xor(p0[hh], 8); p1[hh] += __shfl_xor(p1[hh], 8);
        }
        if (lq == 0) {
            #pragma unroll
            for (int hh = 0; hh < 4; ++hh) {
                Ssc[hh * 256 + m0]     = p0[hh];
                Ssc[hh * 256 + m0 + 4] = p1[hh];
            }
        }
    }
    // same-wave LDS store->load ordering (DS ops are program-ordered per wave)

    // wave-local stats: max + sum(exp) over this wave's 32 rows, per head
    float mxw[4], smw[4];
    #pragma unroll
    for (int h = 0; h < 4; ++h) {
        const float sc = (Ssc[h * 256 + w * 32 + li] + SqkL[h * 256 + w * 32 + li]) * 0.125f;
        float mx = sc;
        #pragma unroll
        for (int mask = 16; mask >= 1; mask >>= 1) mx = fmaxf(mx, __shfl_xor(mx, mask));
        const float e = __expf(sc - mx);
        attn_s[h * 256 + w * 32 + li] = e;   // both 32-halves write identical value
        float sm = e;
        #pragma unroll
        for (int mask = 16; mask >= 1; mask >>= 1) sm += __shfl_xor(sm, mask);
        mxw[h] = mx; smw[h] = sm;
    }
    if (l == 0) {
        #pragma unroll
        for (int h = 0; h < 4; ++h) { mxs[w][h] = mxw[h]; sums[w][h] = smw[h]; }
    }

    // sub-pass 2: A_w[h][d] += e * qv  over this wave's 32 rows
    float4 acc[4];
    #pragma unroll
    for (int hh = 0; hh < 4; ++hh) acc[hh] = make_float4(0.f, 0.f, 0.f, 0.f);
    {
        const float* rb = qv_emb + (size_t)(bn * 256 + w * 32) * 256 + l * 4;
        #pragma unroll
        for (int mm = 0; mm < 32; mm += 8) {
            float4 e[8];
            #pragma unroll
            for (int r = 0; r < 8; ++r)
                e[r] = *reinterpret_cast<const float4*>(rb + (size_t)(mm + r) * 256);
            #pragma unroll
            for (int r = 0; r < 8; ++r) {
                #pragma unroll
                for (int hh = 0; hh < 4; ++hh) {
                    const float a = attn_s[hh * 256 + w * 32 + mm + r];
                    acc[hh].x = fmaf(a, e[r].x, acc[hh].x);
                    acc[hh].y = fmaf(a, e[r].y, acc[hh].y);
                    acc[hh].z = fmaf(a, e[r].z, acc[hh].z);
                    acc[hh].w = fmaf(a, e[r].w, acc[hh].w);
                }
            }
        }
    }
    // ======================= end barrier-free section =======================
    __syncthreads();   // B1: all stats + e's final

    // global merge: scl[w][h] = exp(mx_w - mx_g) / sum_g   (exact softmax)
    if (t < 4) {
        const int h = t;
        float mg = mxs[0][h];
        #pragma unroll
        for (int ww = 1; ww < 8; ++ww) mg = fmaxf(mg, mxs[ww][h]);
        float sr[8]; float sg = 0.f;
        #pragma unroll
        for (int ww = 0; ww < 8; ++ww) { sr[ww] = __expf(mxs[ww][h] - mg); sg += sums[ww][h] * sr[ww]; }
        const float inv = 1.f / sg;
        #pragma unroll
        for (int ww = 0; ww < 8; ++ww) scl[ww][h] = sr[ww] * inv;
    }
    __syncthreads();   // B2: scl ready

    // normalize attn (LDS in place) + write attn output
    {
        const int h = t >> 7, j = t & 127;
        float* ao = attn_out + (size_t)((b * 4 + h) * 256 + n) * 256;
        #pragma unroll
        for (int rep = 0; rep < 2; ++rep) {
            const int jj = j + rep * 128;
            const float a = attn_s[h * 256 + jj] * scl[jj >> 5][h];
            attn_s[h * 256 + jj] = a;
            ao[jj] = a;
        }
    }
    // scaled A partial reduction into Ap
    if (w < 4) {
        #pragma unroll
        for (int hh = 0; hh < 4; ++hh) {
            const float s = scl[w][hh];
            float4 v = acc[hh];
            v.x *= s; v.y *= s; v.z *= s; v.w *= s;
            *reinterpret_cast<float4*>(&Ap[(w * 4 + hh) * 256 + l * 4]) = v;
        }
    }
    __syncthreads();   // B3
    if (w >= 4) {
        #pragma unroll
        for (int hh = 0; hh < 4; ++hh) {
            const float s = scl[w][hh];
            float4* p = reinterpret_cast<float4*>(&Ap[((w - 4) * 4 + hh) * 256 + l * 4]);
            float4 o = *p;
            o.x = fmaf(acc[hh].x, s, o.x); o.y = fmaf(acc[hh].y, s, o.y);
            o.z = fmaf(acc[hh].z, s, o.z); o.w = fmaf(acc[hh].w, s, o.w);
            *p = o;
        }
    }
    __syncthreads();   // B4
    #pragma unroll
    for (int i = 0; i < 2; ++i) {
        const int idx = t + i * 512;
        const int hh = idx >> 8, d = idx & 255;
        Ap[hh * 256 + d] = Ap[hh * 256 + d] + Ap[(4 + hh) * 256 + d]
                         + Ap[(8 + hh) * 256 + d] + Ap[(12 + hh) * 256 + d];
    }

    // ---- phase 4: hidden = attn@v + A@Wqv + bqv, register-double-buffered ----
    {
        const int c = t & 255, half = t >> 8, hc = c >> 6;
        const int fr0 = t >> 6, fc0 = (t & 63) * 4;
        const int fr1 = fr0 + 8;
        const float* vbase = qkvp + (size_t)(1024 + b * 256) * 256;
        float4 ra = *reinterpret_cast<const float4*>(&vbase[(size_t)fr0 * 256 + fc0]);
        float4 rb = *reinterpret_cast<const float4*>(&vbase[(size_t)fr1 * 256 + fc0]);
        float hv = 0.f;
        for (int mt = 0; mt < 16; ++mt) {
            __syncthreads();
            *reinterpret_cast<float4*>(&stage[fr0][fc0]) = ra;
            *reinterpret_cast<float4*>(&stage[fr1][fc0]) = rb;
            if (mt < 15) {
                ra = *reinterpret_cast<const float4*>(&vbase[(size_t)((mt + 1) * 16 + fr0) * 256 + fc0]);
                rb = *reinterpret_cast<const float4*>(&vbase[(size_t)((mt + 1) * 16 + fr1) * 256 + fc0]);
            } else {
                ra = *reinterpret_cast<const float4*>(&Wqv[(size_t)fr0 * 256 + fc0]);
                rb = *reinterpret_cast<const float4*>(&Wqv[(size_t)fr1 * 256 + fc0]);
            }
            __syncthreads();
            #pragma unroll
            for (int r = 0; r < 8; ++r)
                hv = fmaf(attn_s[hc * 256 + mt * 16 + half * 8 + r], stage[half * 8 + r][c], hv);
        }
        for (int dt = 0; dt < 16; ++dt) {
            __syncthreads();
            *reinterpret_cast<float4*>(&stage[fr0][fc0]) = ra;
            *reinterpret_cast<float4*>(&stage[fr1][fc0]) = rb;
            if (dt < 15) {
                ra = *reinterpret_cast<const float4*>(&Wqv[(size_t)((dt + 1) * 16 + fr0) * 256 + fc0]);
                rb = *reinterpret_cast<const float4*>(&Wqv[(size_t)((dt + 1) * 16 + fr1) * 256 + fc0]);
            }
            __syncthreads();
            #pragma unroll
            for (int r = 0; r < 8; ++r)
                hv = fmaf(Ap[hc * 256 + dt * 16 + half * 8 + r], stage[half * 8 + r][c], hv);
        }
        pr[half][c] = hv;
    }
    __syncthreads();
    if (t < 256)
        hidden[(size_t)bn * 256 + t] = pr[0][t] + pr[1][t] + bqv[t];
}

extern "C" void kernel_launch(void* const* d_in, const int* in_sizes, int n_in,
                              void* d_out, int out_size, void* d_ws, size_t ws_size,
                              hipStream_t stream) {
    (void)in_sizes; (void)n_in; (void)out_size; (void)ws_size;
    const float* q_tok  = (const float*)d_in[0];
    const float* k_tok  = (const float*)d_in[1];
    const float* v_tok  = (const float*)d_in[2];
    const float* qk_emb = (const float*)d_in[3];
    const float* qv_emb = (const float*)d_in[4];
    const float* Wq  = (const float*)d_in[5];   const float* bq  = (const float*)d_in[6];
    const float* Wk  = (const float*)d_in[7];   const float* bk  = (const float*)d_in[8];
    const float* Wv  = (const float*)d_in[9];   const float* bv  = (const float*)d_in[10];
    const float* Wqk = (const float*)d_in[11];  /* bqk softmax-invariant */
    const float* Wqv = (const float*)d_in[13];  const float* bqv = (const float*)d_in[14];

    float* ws   = (float*)d_ws;
    float* qkvp = ws;                      // 1536*256 = 393216
    float* qW   = ws + 393216;             // 512*1024 = 524288
    float* Sqk  = ws + 917504;             // 2048*256 = 524288

    float* hidden = (float*)d_out;
    float* attn   = (float*)d_out + BB * NN * CC;

    proj_gemm<<<dim3(24, 4),   256, 0, stream>>>(q_tok, k_tok, v_tok, Wq, bq, Wk, bk, Wv, bv, qkvp);
    qw_gemm  <<<dim3(8, 4, 4), 256, 0, stream>>>(qkvp, Wqk, qW);
    qk_gemm  <<<dim3(4, 4, 8), 256, 0, stream>>>(qkvp, Sqk);
    mega3    <<<512,           512, 0, stream>>>(qk_emb, qv_emb, qkvp, qW, Sqk, Wqv, bqv, attn, hidden);
}

// Round 9
// 91.641 us; speedup vs baseline: 1.2500x; 1.0054x over previous
//
#include <hip/hip_runtime.h>

#define BB 2
#define NN 256
#define CC 256

__device__ __forceinline__ float dot4acc(float4 e, float4 w, float s) {
    s = fmaf(e.x, w.x, s); s = fmaf(e.y, w.y, s);
    s = fmaf(e.z, w.z, s); s = fmaf(e.w, w.w, s);
    return s;
}

// ---------------------------------------------------------------------------
// K1: fused q/k/v projections.  rows 0..511 = q (B*N), 512..1023 = k, 1024..1535 = v
// ---------------------------------------------------------------------------
__global__ __launch_bounds__(256) void proj_gemm(
    const float* __restrict__ q_tok, const float* __restrict__ k_tok, const float* __restrict__ v_tok,
    const float* __restrict__ Wq, const float* __restrict__ bq,
    const float* __restrict__ Wk, const float* __restrict__ bk,
    const float* __restrict__ Wv, const float* __restrict__ bv,
    float* __restrict__ out)
{
    const int row0 = blockIdx.x * 64;
    const int col0 = blockIdx.y * 64;
    const int seg  = row0 >> 9;
    const float* A    = seg == 0 ? q_tok : (seg == 1 ? k_tok : v_tok);
    const float* W    = seg == 0 ? Wq    : (seg == 1 ? Wk    : Wv);
    const float* bias = seg == 0 ? bq    : (seg == 1 ? bk    : bv);
    const int ar0 = row0 & 511;

    __shared__ float As[64][17];
    __shared__ float Bs[16][68];
    const int t  = threadIdx.x;
    const int tr = t >> 4, tc = t & 15;
    float acc[4][4] = {};

    const int sr  = t >> 2, sk4 = (t & 3) << 2;
    const int bkr = t >> 4, bj4 = (t & 15) << 2;

    for (int k0 = 0; k0 < 256; k0 += 16) {
        float4 a4 = *reinterpret_cast<const float4*>(&A[(ar0 + sr) * 256 + k0 + sk4]);
        float4 b4 = *reinterpret_cast<const float4*>(&W[(k0 + bkr) * 256 + col0 + bj4]);
        As[sr][sk4 + 0] = a4.x; As[sr][sk4 + 1] = a4.y; As[sr][sk4 + 2] = a4.z; As[sr][sk4 + 3] = a4.w;
        Bs[bkr][bj4 + 0] = b4.x; Bs[bkr][bj4 + 1] = b4.y; Bs[bkr][bj4 + 2] = b4.z; Bs[bkr][bj4 + 3] = b4.w;
        __syncthreads();
        #pragma unroll
        for (int k = 0; k < 16; ++k) {
            float a[4], bbv[4];
            #pragma unroll
            for (int i = 0; i < 4; ++i) a[i] = As[tr * 4 + i][k];
            #pragma unroll
            for (int j = 0; j < 4; ++j) bbv[j] = Bs[k][tc * 4 + j];
            #pragma unroll
            for (int i = 0; i < 4; ++i)
                #pragma unroll
                for (int j = 0; j < 4; ++j)
                    acc[i][j] = fmaf(a[i], bbv[j], acc[i][j]);
        }
        __syncthreads();
    }
    #pragma unroll
    for (int i = 0; i < 4; ++i) {
        const int r = row0 + tr * 4 + i;
        #pragma unroll
        for (int j = 0; j < 4; ++j) {
            const int cj = col0 + tc * 4 + j;
            out[r * 256 + cj] = acc[i][j] + bias[cj];
        }
    }
}

// ---------------------------------------------------------------------------
// K2: qW[bn][h][d] = sum_c qp[bn][h*64+c] * Wqk[d][h*64+c]   (coalesced tiled)
// ---------------------------------------------------------------------------
__global__ __launch_bounds__(256) void qw_gemm(
    const float* __restrict__ qp, const float* __restrict__ Wqk, float* __restrict__ qW)
{
    const int h    = blockIdx.z;
    const int row0 = blockIdx.x * 64;
    const int d0   = blockIdx.y * 64;
    __shared__ float As[64][17];
    __shared__ float Bs[16][68];
    const int t  = threadIdx.x;
    const int tr = t >> 4, tc = t & 15;
    float acc[4][4] = {};
    const int sr = t >> 2, sc4 = (t & 3) << 2;

    for (int k0 = 0; k0 < 64; k0 += 16) {
        float4 a4 = *reinterpret_cast<const float4*>(&qp[(row0 + sr) * 256 + h * 64 + k0 + sc4]);
        float4 b4 = *reinterpret_cast<const float4*>(&Wqk[(d0 + sr) * 256 + h * 64 + k0 + sc4]);
        As[sr][sc4 + 0] = a4.x; As[sr][sc4 + 1] = a4.y; As[sr][sc4 + 2] = a4.z; As[sr][sc4 + 3] = a4.w;
        Bs[sc4 + 0][sr] = b4.x; Bs[sc4 + 1][sr] = b4.y; Bs[sc4 + 2][sr] = b4.z; Bs[sc4 + 3][sr] = b4.w;
        __syncthreads();
        #pragma unroll
        for (int k = 0; k < 16; ++k) {
            float a[4], bbv[4];
            #pragma unroll
            for (int i = 0; i < 4; ++i) a[i] = As[tr * 4 + i][k];
            #pragma unroll
            for (int j = 0; j < 4; ++j) bbv[j] = Bs[k][tc * 4 + j];
            #pragma unroll
            for (int i = 0; i < 4; ++i)
                #pragma unroll
                for (int j = 0; j < 4; ++j)
                    acc[i][j] = fmaf(a[i], bbv[j], acc[i][j]);
        }
        __syncthreads();
    }
    #pragma unroll
    for (int i = 0; i < 4; ++i)
        #pragma unroll
        for (int j = 0; j < 4; ++j)
            qW[((row0 + tr * 4 + i) * 4 + h) * 256 + d0 + tc * 4 + j] = acc[i][j];
}

// ---------------------------------------------------------------------------
// K3: Sqk[((b*4+h)*256+n)*256+m] = sum_c q[b,n,h*64+c] * k[b,m,h*64+c]  (raw)
// ---------------------------------------------------------------------------
__global__ __launch_bounds__(256) void qk_gemm(
    const float* __restrict__ qkvp, float* __restrict__ Sqk)
{
    const int bh = blockIdx.z;
    const int b  = bh >> 2, h = bh & 3;
    const int n0 = blockIdx.x * 64;
    const int m0 = blockIdx.y * 64;
    __shared__ float As[64][17];
    __shared__ float Bs[16][68];
    const int t  = threadIdx.x;
    const int tr = t >> 4, tc = t & 15;
    float acc[4][4] = {};
    const int sr = t >> 2, sc4 = (t & 3) << 2;

    for (int k0 = 0; k0 < 64; k0 += 16) {
        float4 a4 = *reinterpret_cast<const float4*>(&qkvp[(size_t)(b * 256 + n0 + sr) * 256 + h * 64 + k0 + sc4]);
        float4 b4 = *reinterpret_cast<const float4*>(&qkvp[(size_t)(512 + b * 256 + m0 + sr) * 256 + h * 64 + k0 + sc4]);
        As[sr][sc4 + 0] = a4.x; As[sr][sc4 + 1] = a4.y; As[sr][sc4 + 2] = a4.z; As[sr][sc4 + 3] = a4.w;
        Bs[sc4 + 0][sr] = b4.x; Bs[sc4 + 1][sr] = b4.y; Bs[sc4 + 2][sr] = b4.z; Bs[sc4 + 3][sr] = b4.w;
        __syncthreads();
        #pragma unroll
        for (int k = 0; k < 16; ++k) {
            float a[4], bbv[4];
            #pragma unroll
            for (int i = 0; i < 4; ++i) a[i] = As[tr * 4 + i][k];
            #pragma unroll
            for (int j = 0; j < 4; ++j) bbv[j] = Bs[k][tc * 4 + j];
            #pragma unroll
            for (int i = 0; i < 4; ++i)
                #pragma unroll
                for (int j = 0; j < 4; ++j)
                    acc[i][j] = fmaf(a[i], bbv[j], acc[i][j]);
        }
        __syncthreads();
    }
    #pragma unroll
    for (int i = 0; i < 4; ++i)
        #pragma unroll
        for (int j = 0; j < 4; ++j)
            Sqk[(size_t)((b * 4 + h) * 256 + n0 + tr * 4 + i) * 256 + m0 + tc * 4 + j] = acc[i][j];
}

// ---------------------------------------------------------------------------
// K4: mega4 — mega3 + explicit 2-deep register ping-pong on both streams so
// a 8 KB/wave load batch is ALWAYS in flight while the previous batch is
// consumed (MLP duty ~100% instead of ~50%).
// ---------------------------------------------------------------------------

// load 8 rows' slices for the pair-score pass (lane covers 4 quarters of one
// row in group of 4; two row-groups)
#define S1_LOAD(E00,E01,E02,E03,E10,E11,E12,E13, MB)                          \
    do {                                                                      \
        const float* _r0 = qk_emb + (size_t)(bn * 256 + (MB) + lr) * 256 + lq * 4; \
        const float* _r1 = _r0 + 1024;                                        \
        E00 = *reinterpret_cast<const float4*>(_r0);                          \
        E01 = *reinterpret_cast<const float4*>(_r0 + 64);                     \
        E02 = *reinterpret_cast<const float4*>(_r0 + 128);                    \
        E03 = *reinterpret_cast<const float4*>(_r0 + 192);                    \
        E10 = *reinterpret_cast<const float4*>(_r1);                          \
        E11 = *reinterpret_cast<const float4*>(_r1 + 64);                     \
        E12 = *reinterpret_cast<const float4*>(_r1 + 128);                    \
        E13 = *reinterpret_cast<const float4*>(_r1 + 192);                    \
    } while (0)

#define S1_COMP(E00,E01,E02,E03,E10,E11,E12,E13, MB)                          \
    do {                                                                      \
        const int _m0 = (MB) + lr;                                            \
        float p0[4], p1[4];                                                   \
        _Pragma("unroll")                                                     \
        for (int hh = 0; hh < 4; ++hh) {                                      \
            const float4 w0 = *reinterpret_cast<const float4*>(&qWs[hh * 256 + lq * 4]);        \
            const float4 w1 = *reinterpret_cast<const float4*>(&qWs[hh * 256 + 64 + lq * 4]);   \
            const float4 w2 = *reinterpret_cast<const float4*>(&qWs[hh * 256 + 128 + lq * 4]);  \
            const float4 w3 = *reinterpret_cast<const float4*>(&qWs[hh * 256 + 192 + lq * 4]);  \
            float s0 = 0.f, s1 = 0.f;                                         \
            s0 = dot4acc(E00, w0, s0); s0 = dot4acc(E01, w1, s0);             \
            s0 = dot4acc(E02, w2, s0); s0 = dot4acc(E03, w3, s0);             \
            s1 = dot4acc(E10, w0, s1); s1 = dot4acc(E11, w1, s1);             \
            s1 = dot4acc(E12, w2, s1); s1 = dot4acc(E13, w3, s1);             \
            p0[hh] = s0; p1[hh] = s1;                                         \
        }                                                                     \
        _Pragma("unroll")                                                     \
        for (int hh = 0; hh < 4; ++hh) {                                      \
            p0[hh] += __shfl_xor(p0[hh], 1); p1[hh] += __shfl_xor(p1[hh], 1); \
            p0[hh] += __shfl_xor(p0[hh], 2); p1[hh] += __shfl_xor(p1[hh], 2); \
            p0[hh] += __shfl_xor(p0[hh], 4); p1[hh] += __shfl_xor(p1[hh], 4); \
            p0[hh] += __shfl_xor(p0[hh], 8); p1[hh] += __shfl_xor(p1[hh], 8); \
        }                                                                     \
        if (lq == 0) {                                                        \
            _Pragma("unroll")                                                 \
            for (int hh = 0; hh < 4; ++hh) {                                  \
                Ssc[hh * 256 + _m0]     = p0[hh];                             \
                Ssc[hh * 256 + _m0 + 4] = p1[hh];                             \
            }                                                                 \
        }                                                                     \
    } while (0)

// qv-accum pass: load 8 full-row slices (lane owns d = l*4)
#define S2_LOAD(F0,F1,F2,F3,F4,F5,F6,F7, MB)                                  \
    do {                                                                      \
        const float* _rb = qv_emb + (size_t)(bn * 256 + (MB)) * 256 + l * 4;  \
        F0 = *reinterpret_cast<const float4*>(_rb);                           \
        F1 = *reinterpret_cast<const float4*>(_rb + 256);                     \
        F2 = *reinterpret_cast<const float4*>(_rb + 512);                     \
        F3 = *reinterpret_cast<const float4*>(_rb + 768);                     \
        F4 = *reinterpret_cast<const float4*>(_rb + 1024);                    \
        F5 = *reinterpret_cast<const float4*>(_rb + 1280);                    \
        F6 = *reinterpret_cast<const float4*>(_rb + 1536);                    \
        F7 = *reinterpret_cast<const float4*>(_rb + 1792);                    \
    } while (0)

#define S2_ONE(F, RIDX)                                                       \
    do {                                                                      \
        _Pragma("unroll")                                                     \
        for (int hh = 0; hh < 4; ++hh) {                                      \
            const float a = attn_s[hh * 256 + (RIDX)];                        \
            acc[hh].x = fmaf(a, F.x, acc[hh].x);                              \
            acc[hh].y = fmaf(a, F.y, acc[hh].y);                              \
            acc[hh].z = fmaf(a, F.z, acc[hh].z);                              \
            acc[hh].w = fmaf(a, F.w, acc[hh].w);                              \
        }                                                                     \
    } while (0)

#define S2_COMP(F0,F1,F2,F3,F4,F5,F6,F7, MB)                                  \
    do {                                                                      \
        S2_ONE(F0, (MB) + 0); S2_ONE(F1, (MB) + 1);                           \
        S2_ONE(F2, (MB) + 2); S2_ONE(F3, (MB) + 3);                           \
        S2_ONE(F4, (MB) + 4); S2_ONE(F5, (MB) + 5);                           \
        S2_ONE(F6, (MB) + 6); S2_ONE(F7, (MB) + 7);                           \
    } while (0)

__global__ __launch_bounds__(512, 4) void mega4(
    const float* __restrict__ qk_emb, const float* __restrict__ qv_emb,
    const float* __restrict__ qkvp, const float* __restrict__ qW,
    const float* __restrict__ Sqk, const float* __restrict__ Wqv,
    const float* __restrict__ bqv,
    float* __restrict__ attn_out, float* __restrict__ hidden)
{
    const int bn = blockIdx.x;
    const int b  = bn >> 8, n = bn & 255;
    const int t  = threadIdx.x;
    const int w  = t >> 6, l = t & 63;

    __shared__ float qWs[1024];          // [h][d]
    __shared__ float SqkL[1024];         // [h][m]  raw q.k
    __shared__ float Ssc[1024];          // [h][m]  raw pair scores
    __shared__ float attn_s[1024];       // [h][m]  e -> later normalized attn
    __shared__ float Ap[4096];           // [16][256] A partials; [4][256] after reduce
    __shared__ float stage[16][256];
    __shared__ float pr[2][256];
    __shared__ float mxs[8][4], sums[8][4], scl[8][4];

    // ---- stage qW (contiguous 4 KB) ----
    if (t < 256)
        *reinterpret_cast<float4*>(&qWs[t * 4]) =
            *reinterpret_cast<const float4*>(&qW[(size_t)bn * 1024 + t * 4]);
    __syncthreads();

    const int lq = l & 15, lr = l >> 4, li = l & 31;
    const int mw = w * 32;

    // ================= wave-independent streaming (no barriers) =============
    // this wave's Sqk segment
    if (l < 32) {
        #pragma unroll
        for (int h = 0; h < 4; ++h)
            SqkL[h * 256 + mw + li] =
                Sqk[(size_t)((b * 4 + h) * 256 + n) * 256 + mw + li];
    }

    // ---- sub-pass 1: pair scores, 2-deep ping-pong over 4 batches of 8 rows
    {
        float4 a00, a01, a02, a03, a10, a11, a12, a13;
        float4 b00, b01, b02, b03, b10, b11, b12, b13;
        S1_LOAD(a00,a01,a02,a03,a10,a11,a12,a13, mw + 0);
        S1_LOAD(b00,b01,b02,b03,b10,b11,b12,b13, mw + 8);
        S1_COMP(a00,a01,a02,a03,a10,a11,a12,a13, mw + 0);
        S1_LOAD(a00,a01,a02,a03,a10,a11,a12,a13, mw + 16);
        S1_COMP(b00,b01,b02,b03,b10,b11,b12,b13, mw + 8);
        S1_LOAD(b00,b01,b02,b03,b10,b11,b12,b13, mw + 24);
        S1_COMP(a00,a01,a02,a03,a10,a11,a12,a13, mw + 16);
        S1_COMP(b00,b01,b02,b03,b10,b11,b12,b13, mw + 24);
    }

    // wave-local stats: max + sum(exp) over this wave's 32 rows, per head
    float mxw[4], smw[4];
    #pragma unroll
    for (int h = 0; h < 4; ++h) {
        const float sc = (Ssc[h * 256 + mw + li] + SqkL[h * 256 + mw + li]) * 0.125f;
        float mx = sc;
        #pragma unroll
        for (int mask = 16; mask >= 1; mask >>= 1) mx = fmaxf(mx, __shfl_xor(mx, mask));
        const float e = __expf(sc - mx);
        attn_s[h * 256 + mw + li] = e;   // both 32-halves write identical value
        float sm = e;
        #pragma unroll
        for (int mask = 16; mask >= 1; mask >>= 1) sm += __shfl_xor(sm, mask);
        mxw[h] = mx; smw[h] = sm;
    }
    if (l == 0) {
        #pragma unroll
        for (int h = 0; h < 4; ++h) { mxs[w][h] = mxw[h]; sums[w][h] = smw[h]; }
    }

    // ---- sub-pass 2: A_w[h][d] += e * qv, 2-deep ping-pong ----
    float4 acc[4];
    #pragma unroll
    for (int hh = 0; hh < 4; ++hh) acc[hh] = make_float4(0.f, 0.f, 0.f, 0.f);
    {
        float4 f0, f1, f2, f3, f4, f5, f6, f7;
        float4 g0, g1, g2, g3, g4, g5, g6, g7;
        S2_LOAD(f0,f1,f2,f3,f4,f5,f6,f7, mw + 0);
        S2_LOAD(g0,g1,g2,g3,g4,g5,g6,g7, mw + 8);
        S2_COMP(f0,f1,f2,f3,f4,f5,f6,f7, mw + 0);
        S2_LOAD(f0,f1,f2,f3,f4,f5,f6,f7, mw + 16);
        S2_COMP(g0,g1,g2,g3,g4,g5,g6,g7, mw + 8);
        S2_LOAD(g0,g1,g2,g3,g4,g5,g6,g7, mw + 24);
        S2_COMP(f0,f1,f2,f3,f4,f5,f6,f7, mw + 16);
        S2_COMP(g0,g1,g2,g3,g4,g5,g6,g7, mw + 24);
    }
    // ======================= end barrier-free section =======================
    __syncthreads();   // B1: all stats + e's final

    // global merge: scl[w][h] = exp(mx_w - mx_g) / sum_g   (exact softmax)
    if (t < 4) {
        const int h = t;
        float mg = mxs[0][h];
        #pragma unroll
        for (int ww = 1; ww < 8; ++ww) mg = fmaxf(mg, mxs[ww][h]);
        float sr[8]; float sg = 0.f;
        #pragma unroll
        for (int ww = 0; ww < 8; ++ww) { sr[ww] = __expf(mxs[ww][h] - mg); sg += sums[ww][h] * sr[ww]; }
        const float inv = 1.f / sg;
        #pragma unroll
        for (int ww = 0; ww < 8; ++ww) scl[ww][h] = sr[ww] * inv;
    }
    __syncthreads();   // B2: scl ready

    // normalize attn (LDS in place) + write attn output
    {
        const int h = t >> 7, j = t & 127;
        float* ao = attn_out + (size_t)((b * 4 + h) * 256 + n) * 256;
        #pragma unroll
        for (int rep = 0; rep < 2; ++rep) {
            const int jj = j + rep * 128;
            const float a = attn_s[h * 256 + jj] * scl[jj >> 5][h];
            attn_s[h * 256 + jj] = a;
            ao[jj] = a;
        }
    }
    // scaled A partial reduction into Ap
    if (w < 4) {
        #pragma unroll
        for (int hh = 0; hh < 4; ++hh) {
            const float s = scl[w][hh];
            float4 v = acc[hh];
            v.x *= s; v.y *= s; v.z *= s; v.w *= s;
            *reinterpret_cast<float4*>(&Ap[(w * 4 + hh) * 256 + l * 4]) = v;
        }
    }
    __syncthreads();   // B3
    if (w >= 4) {
        #pragma unroll
        for (int hh = 0; hh < 4; ++hh) {
            const float s = scl[w][hh];
            float4* p = reinterpret_cast<float4*>(&Ap[((w - 4) * 4 + hh) * 256 + l * 4]);
            float4 o = *p;
            o.x = fmaf(acc[hh].x, s, o.x); o.y = fmaf(acc[hh].y, s, o.y);
            o.z = fmaf(acc[hh].z, s, o.z); o.w = fmaf(acc[hh].w, s, o.w);
            *p = o;
        }
    }
    __syncthreads();   // B4
    #pragma unroll
    for (int i = 0; i < 2; ++i) {
        const int idx = t + i * 512;
        const int hh = idx >> 8, d = idx & 255;
        Ap[hh * 256 + d] = Ap[hh * 256 + d] + Ap[(4 + hh) * 256 + d]
                         + Ap[(8 + hh) * 256 + d] + Ap[(12 + hh) * 256 + d];
    }

    // ---- phase 4: hidden = attn@v + A@Wqv + bqv, register-double-buffered ----
    {
        const int c = t & 255, half = t >> 8, hc = c >> 6;
        const int fr0 = t >> 6, fc0 = (t & 63) * 4;
        const int fr1 = fr0 + 8;
        const float* vbase = qkvp + (size_t)(1024 + b * 256) * 256;
        float4 ra = *reinterpret_cast<const float4*>(&vbase[(size_t)fr0 * 256 + fc0]);
        float4 rb = *reinterpret_cast<const float4*>(&vbase[(size_t)fr1 * 256 + fc0]);
        float hv = 0.f;
        for (int mt = 0; mt < 16; ++mt) {
            __syncthreads();
            *reinterpret_cast<float4*>(&stage[fr0][fc0]) = ra;
            *reinterpret_cast<float4*>(&stage[fr1][fc0]) = rb;
            if (mt < 15) {
                ra = *reinterpret_cast<const float4*>(&vbase[(size_t)((mt + 1) * 16 + fr0) * 256 + fc0]);
                rb = *reinterpret_cast<const float4*>(&vbase[(size_t)((mt + 1) * 16 + fr1) * 256 + fc0]);
            } else {
                ra = *reinterpret_cast<const float4*>(&Wqv[(size_t)fr0 * 256 + fc0]);
                rb = *reinterpret_cast<const float4*>(&Wqv[(size_t)fr1 * 256 + fc0]);
            }
            __syncthreads();
            #pragma unroll
            for (int r = 0; r < 8; ++r)
                hv = fmaf(attn_s[hc * 256 + mt * 16 + half * 8 + r], stage[half * 8 + r][c], hv);
        }
        for (int dt = 0; dt < 16; ++dt) {
            __syncthreads();
            *reinterpret_cast<float4*>(&stage[fr0][fc0]) = ra;
            *reinterpret_cast<float4*>(&stage[fr1][fc0]) = rb;
            if (dt < 15) {
                ra = *reinterpret_cast<const float4*>(&Wqv[(size_t)((dt + 1) * 16 + fr0) * 256 + fc0]);
                rb = *reinterpret_cast<const float4*>(&Wqv[(size_t)((dt + 1) * 16 + fr1) * 256 + fc0]);
            }
            __syncthreads();
            #pragma unroll
            for (int r = 0; r < 8; ++r)
                hv = fmaf(Ap[hc * 256 + dt * 16 + half * 8 + r], stage[half * 8 + r][c], hv);
        }
        pr[half][c] = hv;
    }
    __syncthreads();
    if (t < 256)
        hidden[(size_t)bn * 256 + t] = pr[0][t] + pr[1][t] + bqv[t];
}

extern "C" void kernel_launch(void* const* d_in, const int* in_sizes, int n_in,
                              void* d_out, int out_size, void* d_ws, size_t ws_size,
                              hipStream_t stream) {
    (void)in_sizes; (void)n_in; (void)out_size; (void)ws_size;
    const float* q_tok  = (const float*)d_in[0];
    const float* k_tok  = (const float*)d_in[1];
    const float* v_tok  = (const float*)d_in[2];
    const float* qk_emb = (const float*)d_in[3];
    const float* qv_emb = (const float*)d_in[4];
    const float* Wq  = (const float*)d_in[5];   const float* bq  = (const float*)d_in[6];
    const float* Wk  = (const float*)d_in[7];   const float* bk  = (const float*)d_in[8];
    const float* Wv  = (const float*)d_in[9];   const float* bv  = (const float*)d_in[10];
    const float* Wqk = (const float*)d_in[11];  /* bqk softmax-invariant */
    const float* Wqv = (const float*)d_in[13];  const float* bqv = (const float*)d_in[14];

    float* ws   = (float*)d_ws;
    float* qkvp = ws;                      // 1536*256 = 393216
    float* qW   = ws + 393216;             // 512*1024 = 524288
    float* Sqk  = ws + 917504;             // 2048*256 = 524288

    float* hidden = (float*)d_out;
    float* attn   = (float*)d_out + BB * NN * CC;

    proj_gemm<<<dim3(24, 4),   256, 0, stream>>>(q_tok, k_tok, v_tok, Wq, bq, Wk, bk, Wv, bv, qkvp);
    qw_gemm  <<<dim3(8, 4, 4), 256, 0, stream>>>(qkvp, Wqk, qW);
    qk_gemm  <<<dim3(4, 4, 8), 256, 0, stream>>>(qkvp, Sqk);
    mega4    <<<512,           512, 0, stream>>>(qk_emb, qv_emb, qkvp, qW, Sqk, Wqv, bqv, attn, hidden);
}